// Round 19
// baseline (326.431 us; speedup 1.0000x reference)
//
#include <hip/hip_runtime.h>
#include <math.h>

typedef __attribute__((ext_vector_type(8))) short short8;
typedef __attribute__((ext_vector_type(4))) short short4v;
typedef __attribute__((ext_vector_type(4))) float f32x4;

namespace {

constexpr int kT = 12, kMS = 20, kE = 3;
constexpr int kSites = 64 * 325;                 // 20800
constexpr int kWaves = 8;
constexpr int kThreads = kWaves * 64;            // 512
constexpr int kNB = 768;                         // 3 blocks/CU target (no-LDS kernel)
constexpr int kStride = kNB * kWaves;            // 6144
constexpr int kIters = 4;                        // ceil(20800/6144), even -> unroll-2

// d_ws layout: wfrag[3][2][12][512] u16 (73728 B) + G[32][4] f32 (512 B)
constexpr int kWfElems = kE * 2 * 12 * 512;      // 36864 shorts
constexpr int kGOff = kWfElems;                  // in shorts; G starts at byte 73728

__device__ __forceinline__ void split1(float x, unsigned& hi, unsigned& lo) {
  unsigned u = __float_as_uint(x);
  hi = u >> 16;
  float r = x - __uint_as_float(u & 0xFFFF0000u);   // exact (Sterbenz)
  lo = __float_as_uint(r) >> 16;
}
__device__ __forceinline__ float btrunc(float x) {
  return __uint_as_float(__float_as_uint(x) & 0xFFFF0000u);
}
__device__ __forceinline__ unsigned pk_hi(float a, float b) {   // {bf(b):bf(a)}, a low
  return __builtin_amdgcn_perm(__float_as_uint(b), __float_as_uint(a), 0x07060302u);
}
__device__ __forceinline__ unsigned pk_rnd(float a, float b) {  // round-half-up bf16 pack
  return __builtin_amdgcn_perm(__float_as_uint(b) + 0x8000u,
                               __float_as_uint(a) + 0x8000u, 0x07060302u);
}

union S8 { short8 s; unsigned u[4]; };
union S4 { short4v s; unsigned u[2]; };

#define MFMA32(a, b, c) __builtin_amdgcn_mfma_f32_16x16x32_bf16((a), (b), (c), 0, 0, 0)
// gfx90a+ name on gfx950. No __has_builtin guard — false in the HIP host pass (R10).
#define MFMA16(a, b, c) __builtin_amdgcn_mfma_f32_16x16x16bf16_1k((a), (b), (c), 0, 0, 0)

// ---- pre-kernel: split weights into hi/lo frag layout + G into d_ws ----
__global__ __launch_bounds__(kThreads) void testam_prep(
    const float* __restrict__ memw, const float* __restrict__ iq,
    const float* __restrict__ hq, const float* __restrict__ kwt,
    const float* __restrict__ vw, unsigned short* __restrict__ wf,
    float* __restrict__ G) {
  const int tid = threadIdx.x;
  for (int idx = tid; idx < kE * 768; idx += kThreads) {
    int e2 = idx / 768, rem = idx - e2 * 768;
    int ll = rem & 63, fi = rem >> 6;
    int mat = fi >> 2, x = (fi >> 1) & 1, y = fi & 1;
    int gg = ll >> 4, cc = ll & 15;
    const float* wp = ((mat == 0) ? hq : (mat == 1) ? kwt : vw) + e2 * 2048
                      + (y * 32 + gg * 8) * 32 + x * 16 + cc;
    short8 sh, sl;
    #pragma unroll
    for (int j = 0; j < 8; ++j) {
      unsigned h, lo; split1(wp[j * 32], h, lo);
      sh[j] = (short)h; sl[j] = (short)lo;
    }
    *(short8*)&wf[((e2 * 2 + 0) * 12 + fi) * 512 + ll * 8] = sh;
    *(short8*)&wf[((e2 * 2 + 1) * 12 + fi) * 512 + ll * 8] = sl;
  }
  for (int idx = tid; idx < 128; idx += kThreads) {
    int s = idx >> 2, d = idx & 3;
    float acc = 0.f;
    if (d < 3 && s < kMS) {
      for (int m = 0; m < 32; ++m) acc += iq[d * 32 + m] * memw[s * 32 + m];
    }
    G[idx] = acc;
  }
}

// Layouts (m89-verified K=32; classic K=16):
//   K=32 A: lane holds A[row=l&15][k=8g+j]; B: B[k=8g+j][col=l&15]
//   K=16 A: lane holds A[row=l&15][k=4g+j]; B: B[k=4g+j][col=l&15]
//   C/D (both): lane holds D[row=4g+r][col=l&15]
// => C-regs of X == A-frag(K=16) of X^T == B-frag(K=16) of X.  (zero-move chaining)
// R12 lesson: no big register hoists (+48 VGPR -> scratch spill).
// R13: MFMA chain-splitting neutral. R18: mem path deduped (once per site).
// R19: weight frags live in L2-resident d_ws -> zero LDS -> 24 waves/CU cap.
__global__ __launch_bounds__(kThreads, 6) void testam_mfma(
    const float* __restrict__ input, const float* __restrict__ h0,
    const float* __restrict__ h1, const float* __restrict__ h2,
    const float* __restrict__ memw,
    const unsigned short* __restrict__ wf, const float* __restrict__ G,
    float* __restrict__ out) {

  const int tid = threadIdx.x;
  const int b = blockIdx.x;
  const int l = tid & 63, wv = tid >> 6;
  const int g = l >> 4, c = l & 15;

  // ---- memw^T A-frags (K=16) straight into registers (once) ----
  S4 mwh[2][2], mwl[2][2];
  #pragma unroll
  for (int p = 0; p < 2; ++p)
    #pragma unroll
    for (int sch = 0; sch < 2; ++sch) {
      float v[4];
      #pragma unroll
      for (int j = 0; j < 4; ++j) {
        int s = 16 * sch + 4 * g + j;
        v[j] = (s < kMS) ? memw[s * 32 + 16 * p + c] : 0.f;
      }
      mwh[p][sch].u[0] = pk_hi(v[0], v[1]);
      mwh[p][sch].u[1] = pk_hi(v[2], v[3]);
      mwl[p][sch].u[0] = pk_hi(v[0] - btrunc(v[0]), v[1] - btrunc(v[1]));
      mwl[p][sch].u[1] = pk_hi(v[2] - btrunc(v[2]), v[3] - btrunc(v[3]));
    }

  const f32x4 fz = {0.f, 0.f, 0.f, 0.f};

  // lanes c>=12 read row 0 (finite); s>=12 slots meet exact-zero weights.
  const int crow = (c < kT) ? c : 0;

  auto load_h = [&](const float* hb, int s, float* hr) {
    const int sc_ = (s < kSites) ? s : (kSites - 1);
    const float* p = hb + (size_t)sc_ * 768 + crow * 64 + g * 8;
    *(f32x4*)&hr[0]  = *(const f32x4*)&p[0];
    *(f32x4*)&hr[4]  = *(const f32x4*)&p[4];
    *(f32x4*)&hr[8]  = *(const f32x4*)&p[32];
    *(f32x4*)&hr[12] = *(const f32x4*)&p[36];
  };
  auto load_p = [&](int s, float* pr) {
    const int sc_ = (s < kSites) ? s : (kSites - 1);
    const float* ip = input + (size_t)sc_ * 36 + crow * 3;
    pr[0] = ip[0]; pr[1] = ip[1]; pr[2] = ip[2];
  };

  // ---- expert-invariant memory path: pv -> cmem[2] (once per site) ----
  auto memfn = [&](const float* pv, f32x4* cmem) {
    float sc0[4], sc1[4];
    #pragma unroll
    for (int r = 0; r < 4; ++r) {
      const f32x4 Gv0 = *(const f32x4*)&G[(4 * g + r) * 4];
      sc0[r] = pv[0] * Gv0[0] + pv[1] * Gv0[1] + pv[2] * Gv0[2];
      const f32x4 Gv1 = *(const f32x4*)&G[(16 + 4 * g + r) * 4];
      sc1[r] = pv[0] * Gv1[0] + pv[1] * Gv1[1] + pv[2] * Gv1[2];
    }
    float w0[4], w1[4];
    {
      float mloc = sc0[0];
      #pragma unroll
      for (int r = 1; r < 4; ++r) mloc = fmaxf(mloc, sc0[r]);
      if (g == 0) {
        #pragma unroll
        for (int r = 0; r < 4; ++r) mloc = fmaxf(mloc, sc1[r]);
      }
      float mx = mloc;
      mx = fmaxf(mx, __shfl_xor(mx, 16));
      mx = fmaxf(mx, __shfl_xor(mx, 32));
      float sloc = 0.f;
      #pragma unroll
      for (int r = 0; r < 4; ++r) {
        w0[r] = __expf(sc0[r] - mx); sloc += w0[r];
        w1[r] = (g == 0) ? __expf(sc1[r] - mx) : 0.f; sloc += w1[r];
      }
      float sm = sloc;
      sm += __shfl_xor(sm, 16);
      sm += __shfl_xor(sm, 32);
      float inv = 1.f / sm;
      #pragma unroll
      for (int r = 0; r < 4; ++r) { w0[r] *= inv; w1[r] *= inv; }
    }
    S4 w0h, w0l, w1h, w1l;
    w0h.u[0] = pk_hi(w0[0], w0[1]);  w0h.u[1] = pk_hi(w0[2], w0[3]);
    w0l.u[0] = pk_hi(w0[0] - btrunc(w0[0]), w0[1] - btrunc(w0[1]));
    w0l.u[1] = pk_hi(w0[2] - btrunc(w0[2]), w0[3] - btrunc(w0[3]));
    w1h.u[0] = pk_hi(w1[0], w1[1]);  w1h.u[1] = pk_hi(w1[2], w1[3]);
    w1l.u[0] = pk_hi(w1[0] - btrunc(w1[0]), w1[1] - btrunc(w1[1]));
    w1l.u[1] = pk_hi(w1[2] - btrunc(w1[2]), w1[3] - btrunc(w1[3]));
    #pragma unroll
    for (int p = 0; p < 2; ++p) {
      cmem[p] = MFMA16(mwh[p][0].s, w0h.s, fz);
      cmem[p] = MFMA16(mwh[p][0].s, w0l.s, cmem[p]);
      cmem[p] = MFMA16(mwl[p][0].s, w0h.s, cmem[p]);
      cmem[p] = MFMA16(mwh[p][1].s, w1h.s, cmem[p]);
      cmem[p] = MFMA16(mwh[p][1].s, w1l.s, cmem[p]);
      cmem[p] = MFMA16(mwl[p][1].s, w1h.s, cmem[p]);
    }
  };

  // ---- per-(site, expert) attention path + cosine + store ----
  auto body = [&](int site, int e, const float* hv, const f32x4* cmem) {
    const unsigned short* wfe = wf + (size_t)e * (2 * 12 * 512);

    S8 ah[2], al[2];
    #pragma unroll
    for (int k0i = 0; k0i < 2; ++k0i)
      #pragma unroll
      for (int jj = 0; jj < 4; ++jj) {
        float a = hv[k0i * 8 + 2 * jj], bb = hv[k0i * 8 + 2 * jj + 1];
        ah[k0i].u[jj] = pk_hi(a, bb);
        al[k0i].u[jj] = pk_hi(a - btrunc(a), bb - btrunc(bb));
      }

    f32x4 cq[2] = {fz, fz}, ck[2] = {fz, fz}, cv[2] = {fz, fz};
    __builtin_amdgcn_s_setprio(1);
    #pragma unroll
    for (int p = 0; p < 2; ++p)
      #pragma unroll
      for (int k0i = 0; k0i < 2; ++k0i) {
        {
          const int fi = 0 + p * 2 + k0i;
          short8 wh = *(const short8*)&wfe[(0 * 12 + fi) * 512 + l * 8];
          short8 wlo = *(const short8*)&wfe[(1 * 12 + fi) * 512 + l * 8];
          cq[p] = MFMA32(wh, ah[k0i].s, cq[p]);
          cq[p] = MFMA32(wh, al[k0i].s, cq[p]);
          cq[p] = MFMA32(wlo, ah[k0i].s, cq[p]);
        }
        {
          const int fi = 4 + p * 2 + k0i;
          short8 wh = *(const short8*)&wfe[(0 * 12 + fi) * 512 + l * 8];
          short8 wlo = *(const short8*)&wfe[(1 * 12 + fi) * 512 + l * 8];
          ck[p] = MFMA32(wh, ah[k0i].s, ck[p]);
          ck[p] = MFMA32(wh, al[k0i].s, ck[p]);
          ck[p] = MFMA32(wlo, ah[k0i].s, ck[p]);
        }
        {
          const int fi = 8 + p * 2 + k0i;
          short8 wh = *(const short8*)&wfe[(0 * 12 + fi) * 512 + l * 8];
          short8 wlo = *(const short8*)&wfe[(1 * 12 + fi) * 512 + l * 8];
          cv[p] = MFMA32(ah[k0i].s, wh, cv[p]);
          cv[p] = MFMA32(ah[k0i].s, wlo, cv[p]);
          cv[p] = MFMA32(al[k0i].s, wh, cv[p]);
        }
      }
    __builtin_amdgcn_s_setprio(0);

    S4 cqh[2], cql[2], ckh[2], ckl[2], va[2];
    #pragma unroll
    for (int p = 0; p < 2; ++p) {
      cqh[p].u[0] = pk_hi(cq[p][0], cq[p][1]);
      cqh[p].u[1] = pk_hi(cq[p][2], cq[p][3]);
      cql[p].u[0] = pk_hi(cq[p][0] - btrunc(cq[p][0]), cq[p][1] - btrunc(cq[p][1]));
      cql[p].u[1] = pk_hi(cq[p][2] - btrunc(cq[p][2]), cq[p][3] - btrunc(cq[p][3]));
      ckh[p].u[0] = pk_hi(ck[p][0], ck[p][1]);
      ckh[p].u[1] = pk_hi(ck[p][2], ck[p][3]);
      ckl[p].u[0] = pk_hi(ck[p][0] - btrunc(ck[p][0]), ck[p][1] - btrunc(ck[p][1]));
      ckl[p].u[1] = pk_hi(ck[p][2] - btrunc(ck[p][2]), ck[p][3] - btrunc(ck[p][3]));
      va[p].u[0] = pk_rnd(cv[p][0], cv[p][1]);
      va[p].u[1] = pk_rnd(cv[p][2], cv[p][3]);
    }

    f32x4 eng = fz;
    #pragma unroll
    for (int p = 0; p < 2; ++p) {
      eng = MFMA16(ckh[p].s, cqh[p].s, eng);
      eng = MFMA16(ckh[p].s, cql[p].s, eng);
      eng = MFMA16(ckl[p].s, cqh[p].s, eng);
    }

    float w[4];
    {
      float mloc = -1e30f;
      if (g < 3) {
        mloc = eng[0];
        #pragma unroll
        for (int r = 1; r < 4; ++r) mloc = fmaxf(mloc, eng[r]);
      }
      float mx = mloc;
      mx = fmaxf(mx, __shfl_xor(mx, 16));
      mx = fmaxf(mx, __shfl_xor(mx, 32));
      float sloc = 0.f;
      #pragma unroll
      for (int r = 0; r < 4; ++r) {
        w[r] = (g < 3) ? __expf(eng[r] - mx) : 0.f;
        sloc += w[r];
      }
      float sm = sloc;
      sm += __shfl_xor(sm, 16);
      sm += __shfl_xor(sm, 32);
      float inv = 1.f / sm;
      #pragma unroll
      for (int r = 0; r < 4; ++r) w[r] *= inv;
    }

    S4 wh_, wl_;
    wh_.u[0] = pk_hi(w[0], w[1]);
    wh_.u[1] = pk_hi(w[2], w[3]);
    wl_.u[0] = pk_hi(w[0] - btrunc(w[0]), w[1] - btrunc(w[1]));
    wl_.u[1] = pk_hi(w[2] - btrunc(w[2]), w[3] - btrunc(w[3]));
    f32x4 hat[2];
    #pragma unroll
    for (int p = 0; p < 2; ++p) {
      hat[p] = MFMA16(va[p].s, wh_.s, fz);
      hat[p] = MFMA16(va[p].s, wl_.s, hat[p]);
    }

    float dot = 0.f, na = 0.f, nb = 0.f;
    #pragma unroll
    for (int p = 0; p < 2; ++p)
      #pragma unroll
      for (int r = 0; r < 4; ++r) {
        float a = cmem[p][r], h = hat[p][r];
        dot += a * h; na += a * a; nb += h * h;
      }
    dot += __shfl_xor(dot, 16); dot += __shfl_xor(dot, 32);
    na  += __shfl_xor(na, 16);  na  += __shfl_xor(na, 32);
    nb  += __shfl_xor(nb, 16);  nb  += __shfl_xor(nb, 32);
    if (g == 0 && c < kT) {
      float cvv = dot / fmaxf(sqrtf(na) * sqrtf(nb), 1e-8f);
      out[(size_t)site * (kT * kE) + c * kE + e] = cvv;
    }
  };

  // ---- unroll-2 site sweep; 6 tasks/group, strict hA/hB alternation ----
  float hA[16], hB[16], pA[3], pB[3];
  f32x4 cmem[2];
  int site = b * kWaves + wv;
  load_h(h0, site, hA);
  load_p(site, pA);
  for (int it = 0; it < kIters; it += 2) {
    const int s1 = site, s2 = site + kStride;
    // s1: e0(hA) e1(hB) e2(hA)
    load_h(h1, s1, hB);
    if (s1 < kSites) { memfn(pA, cmem); body(s1, 0, hA, cmem); }
    load_h(h2, s1, hA);
    if (s1 < kSites) body(s1, 1, hB, cmem);
    load_h(h0, s2, hB);
    load_p(s2, pB);
    if (s1 < kSites) body(s1, 2, hA, cmem);
    // s2: e0(hB) e1(hA) e2(hB)
    load_h(h1, s2, hA);
    if (s2 < kSites) { memfn(pB, cmem); body(s2, 0, hB, cmem); }
    load_h(h2, s2, hB);
    if (s2 < kSites) body(s2, 1, hA, cmem);
    load_h(h0, s2 + kStride, hA);
    load_p(s2 + kStride, pA);
    if (s2 < kSites) body(s2, 2, hB, cmem);
    site += 2 * kStride;
  }
}

}  // namespace

extern "C" void kernel_launch(void* const* d_in, const int* in_sizes, int n_in,
                              void* d_out, int out_size, void* d_ws, size_t ws_size,
                              hipStream_t stream) {
  const float* input = (const float*)d_in[0];
  const float* h0    = (const float*)d_in[1];
  const float* h1    = (const float*)d_in[2];
  const float* h2    = (const float*)d_in[3];
  const float* memw  = (const float*)d_in[4];
  const float* iq    = (const float*)d_in[5];
  const float* hq    = (const float*)d_in[6];
  const float* kw    = (const float*)d_in[7];
  const float* vw    = (const float*)d_in[8];
  float* out = (float*)d_out;

  unsigned short* wf = (unsigned short*)d_ws;           // 73728 B
  float* G = (float*)((char*)d_ws + kWfElems * 2);      // 512 B

  testam_prep<<<1, kThreads, 0, stream>>>(memw, iq, hq, kw, vw, wf, G);
  testam_mfma<<<kNB, kThreads, 0, stream>>>(input, h0, h1, h2, memw, wf, G, out);
}

// Round 20
// 118.680 us; speedup vs baseline: 2.7505x; 2.7505x over previous
//
#include <hip/hip_runtime.h>
#include <math.h>

typedef __attribute__((ext_vector_type(8))) short short8;
typedef __attribute__((ext_vector_type(4))) short short4v;
typedef __attribute__((ext_vector_type(4))) float f32x4;

namespace {

constexpr int kT = 12, kMS = 20, kE = 3;
constexpr int kSites = 64 * 325;                 // 20800
constexpr int kWaves = 8;
constexpr int kThreads = kWaves * 64;            // 512
constexpr int kNB = 512;                         // blocks; LDS 37.4KB -> up to 4/CU
constexpr int kStride = kNB * kWaves;            // 4096
constexpr int kIters = (kSites + kStride - 1) / kStride;  // 6 (even -> unroll-2 clean)

__device__ __forceinline__ void split1(float x, unsigned& hi, unsigned& lo) {
  unsigned u = __float_as_uint(x);
  hi = u >> 16;
  float r = x - __uint_as_float(u & 0xFFFF0000u);   // exact (Sterbenz)
  lo = __float_as_uint(r) >> 16;
}
__device__ __forceinline__ float btrunc(float x) {
  return __uint_as_float(__float_as_uint(x) & 0xFFFF0000u);
}
__device__ __forceinline__ unsigned pk_hi(float a, float b) {   // {bf(b):bf(a)}, a low
  return __builtin_amdgcn_perm(__float_as_uint(b), __float_as_uint(a), 0x07060302u);
}
__device__ __forceinline__ unsigned pk_rnd(float a, float b) {  // round-half-up bf16 pack
  return __builtin_amdgcn_perm(__float_as_uint(b) + 0x8000u,
                               __float_as_uint(a) + 0x8000u, 0x07060302u);
}

union S8 { short8 s; unsigned u[4]; };
union S4 { short4v s; unsigned u[2]; };

#define MFMA32(a, b, c) __builtin_amdgcn_mfma_f32_16x16x32_bf16((a), (b), (c), 0, 0, 0)
// gfx90a+ name on gfx950. No __has_builtin guard — false in the HIP host pass (R10).
#define MFMA16(a, b, c) __builtin_amdgcn_mfma_f32_16x16x16bf16_1k((a), (b), (c), 0, 0, 0)

// ---- prep: lo-plane weight frags -> d_ws (L2-hot, 36864 B) ----
__global__ __launch_bounds__(kThreads) void testam_prep(
    const float* __restrict__ hq, const float* __restrict__ kwt,
    const float* __restrict__ vw, unsigned short* __restrict__ wflo) {
  const int tid = threadIdx.x;
  for (int idx = tid; idx < kE * 768; idx += kThreads) {
    int e2 = idx / 768, rem = idx - e2 * 768;
    int ll = rem & 63, fi = rem >> 6;
    int mat = fi >> 2, x = (fi >> 1) & 1, y = fi & 1;
    int gg = ll >> 4, cc = ll & 15;
    const float* wp = ((mat == 0) ? hq : (mat == 1) ? kwt : vw) + e2 * 2048
                      + (y * 32 + gg * 8) * 32 + x * 16 + cc;
    short8 sl;
    #pragma unroll
    for (int j = 0; j < 8; ++j) {
      unsigned h, lo; split1(wp[j * 32], h, lo);
      sl[j] = (short)lo;
    }
    *(short8*)&wflo[(e2 * 12 + fi) * 512 + ll * 8] = sl;
  }
}

// Layouts (m89-verified K=32; classic K=16):
//   K=32 A: lane holds A[row=l&15][k=8g+j]; B: B[k=8g+j][col=l&15]
//   K=16 A: lane holds A[row=l&15][k=4g+j]; B: B[k=4g+j][col=l&15]
//   C/D (both): lane holds D[row=4g+r][col=l&15]
// => C-regs of X == A-frag(K=16) of X^T == B-frag(K=16) of X.  (zero-move chaining)
// R8/R12/R19 lesson (x3): __launch_bounds__ >=6 => allocator pins low VGPR and
// SPILLS catastrophically. Bounds stay at 4. R13: chain-split neutral.
// R18: mem path deduped. R20: hi-plane LDS (37KB, 4 blk/CU) + lo-plane L2.
__global__ __launch_bounds__(kThreads, 4) void testam_mfma(
    const float* __restrict__ input, const float* __restrict__ h0,
    const float* __restrict__ h1, const float* __restrict__ h2,
    const float* __restrict__ memw, const float* __restrict__ iq,
    const float* __restrict__ hq, const float* __restrict__ kwt,
    const float* __restrict__ vw, const unsigned short* __restrict__ wflo,
    float* __restrict__ out) {

  __shared__ __align__(16) unsigned short wldsHi[kE][12][512];  // 36864 B
  __shared__ __align__(16) float Glds[32][4];                   // 512 B

  const int tid = threadIdx.x;
  const int b = blockIdx.x;
  const int l = tid & 63, wv = tid >> 6;
  const int g = l >> 4, c = l & 15;

  // ---- one-time staging: hi-plane frags into LDS ----
  for (int idx = tid; idx < kE * 768; idx += kThreads) {
    int e2 = idx / 768, rem = idx - e2 * 768;
    int ll = rem & 63, fi = rem >> 6;
    int mat = fi >> 2, x = (fi >> 1) & 1, y = fi & 1;
    int gg = ll >> 4, cc = ll & 15;
    const float* wp = ((mat == 0) ? hq : (mat == 1) ? kwt : vw) + e2 * 2048
                      + (y * 32 + gg * 8) * 32 + x * 16 + cc;
    short8 sh;
    #pragma unroll
    for (int j = 0; j < 8; ++j) {
      unsigned h, lo; split1(wp[j * 32], h, lo);
      sh[j] = (short)h;
    }
    *(short8*)&wldsHi[e2][fi][ll * 8] = sh;
  }
  for (int idx = tid; idx < 128; idx += kThreads) {
    int s = idx >> 2, d = idx & 3;
    float acc = 0.f;
    if (d < 3 && s < kMS) {
      for (int m = 0; m < 32; ++m) acc += iq[d * 32 + m] * memw[s * 32 + m];
    }
    Glds[s][d] = acc;
  }

  // ---- memw^T A-frags (K=16) straight into registers (once) ----
  S4 mwh[2][2], mwl[2][2];
  #pragma unroll
  for (int p = 0; p < 2; ++p)
    #pragma unroll
    for (int sch = 0; sch < 2; ++sch) {
      float v[4];
      #pragma unroll
      for (int j = 0; j < 4; ++j) {
        int s = 16 * sch + 4 * g + j;
        v[j] = (s < kMS) ? memw[s * 32 + 16 * p + c] : 0.f;
      }
      mwh[p][sch].u[0] = pk_hi(v[0], v[1]);
      mwh[p][sch].u[1] = pk_hi(v[2], v[3]);
      mwl[p][sch].u[0] = pk_hi(v[0] - btrunc(v[0]), v[1] - btrunc(v[1]));
      mwl[p][sch].u[1] = pk_hi(v[2] - btrunc(v[2]), v[3] - btrunc(v[3]));
    }
  __syncthreads();

  const f32x4 fz = {0.f, 0.f, 0.f, 0.f};

  // lanes c>=12 read row 0 (finite); s>=12 slots meet exact-zero weights.
  const int crow = (c < kT) ? c : 0;

  auto load_h = [&](const float* hb, int s, float* hr) {
    const int sc_ = (s < kSites) ? s : (kSites - 1);
    const float* p = hb + (size_t)sc_ * 768 + crow * 64 + g * 8;
    *(f32x4*)&hr[0]  = *(const f32x4*)&p[0];
    *(f32x4*)&hr[4]  = *(const f32x4*)&p[4];
    *(f32x4*)&hr[8]  = *(const f32x4*)&p[32];
    *(f32x4*)&hr[12] = *(const f32x4*)&p[36];
  };
  auto load_p = [&](int s, float* pr) {
    const int sc_ = (s < kSites) ? s : (kSites - 1);
    const float* ip = input + (size_t)sc_ * 36 + crow * 3;
    pr[0] = ip[0]; pr[1] = ip[1]; pr[2] = ip[2];
  };

  // ---- expert-invariant memory path: pv -> cmem[2] (once per site) ----
  auto memfn = [&](const float* pv, f32x4* cmem) {
    float sc0[4], sc1[4];
    #pragma unroll
    for (int r = 0; r < 4; ++r) {
      const f32x4 Gv0 = *(const f32x4*)&Glds[4 * g + r][0];
      sc0[r] = pv[0] * Gv0[0] + pv[1] * Gv0[1] + pv[2] * Gv0[2];
      const f32x4 Gv1 = *(const f32x4*)&Glds[16 + 4 * g + r][0];
      sc1[r] = pv[0] * Gv1[0] + pv[1] * Gv1[1] + pv[2] * Gv1[2];
    }
    float w0[4], w1[4];
    {
      float mloc = sc0[0];
      #pragma unroll
      for (int r = 1; r < 4; ++r) mloc = fmaxf(mloc, sc0[r]);
      if (g == 0) {
        #pragma unroll
        for (int r = 0; r < 4; ++r) mloc = fmaxf(mloc, sc1[r]);
      }
      float mx = mloc;
      mx = fmaxf(mx, __shfl_xor(mx, 16));
      mx = fmaxf(mx, __shfl_xor(mx, 32));
      float sloc = 0.f;
      #pragma unroll
      for (int r = 0; r < 4; ++r) {
        w0[r] = __expf(sc0[r] - mx); sloc += w0[r];
        w1[r] = (g == 0) ? __expf(sc1[r] - mx) : 0.f; sloc += w1[r];
      }
      float sm = sloc;
      sm += __shfl_xor(sm, 16);
      sm += __shfl_xor(sm, 32);
      float inv = 1.f / sm;
      #pragma unroll
      for (int r = 0; r < 4; ++r) { w0[r] *= inv; w1[r] *= inv; }
    }
    S4 w0h, w0l, w1h, w1l;
    w0h.u[0] = pk_hi(w0[0], w0[1]);  w0h.u[1] = pk_hi(w0[2], w0[3]);
    w0l.u[0] = pk_hi(w0[0] - btrunc(w0[0]), w0[1] - btrunc(w0[1]));
    w0l.u[1] = pk_hi(w0[2] - btrunc(w0[2]), w0[3] - btrunc(w0[3]));
    w1h.u[0] = pk_hi(w1[0], w1[1]);  w1h.u[1] = pk_hi(w1[2], w1[3]);
    w1l.u[0] = pk_hi(w1[0] - btrunc(w1[0]), w1[1] - btrunc(w1[1]));
    w1l.u[1] = pk_hi(w1[2] - btrunc(w1[2]), w1[3] - btrunc(w1[3]));
    #pragma unroll
    for (int p = 0; p < 2; ++p) {
      cmem[p] = MFMA16(mwh[p][0].s, w0h.s, fz);
      cmem[p] = MFMA16(mwh[p][0].s, w0l.s, cmem[p]);
      cmem[p] = MFMA16(mwl[p][0].s, w0h.s, cmem[p]);
      cmem[p] = MFMA16(mwh[p][1].s, w1h.s, cmem[p]);
      cmem[p] = MFMA16(mwh[p][1].s, w1l.s, cmem[p]);
      cmem[p] = MFMA16(mwl[p][1].s, w1h.s, cmem[p]);
    }
  };

  // ---- per-(site, expert) attention path + cosine + store ----
  auto body = [&](int site, int e, const float* hv, const f32x4* cmem) {
    const unsigned short* wfe = wflo + (size_t)e * (12 * 512);

    S8 ah[2], al[2];
    #pragma unroll
    for (int k0i = 0; k0i < 2; ++k0i)
      #pragma unroll
      for (int jj = 0; jj < 4; ++jj) {
        float a = hv[k0i * 8 + 2 * jj], bb = hv[k0i * 8 + 2 * jj + 1];
        ah[k0i].u[jj] = pk_hi(a, bb);
        al[k0i].u[jj] = pk_hi(a - btrunc(a), bb - btrunc(bb));
      }

    f32x4 cq[2] = {fz, fz}, ck[2] = {fz, fz}, cv[2] = {fz, fz};
    __builtin_amdgcn_s_setprio(1);
    #pragma unroll
    for (int p = 0; p < 2; ++p)
      #pragma unroll
      for (int k0i = 0; k0i < 2; ++k0i) {
        {
          const int fi = 0 + p * 2 + k0i;
          short8 wh = *(const short8*)&wldsHi[e][fi][l * 8];
          short8 wlo = *(const short8*)&wfe[fi * 512 + l * 8];
          cq[p] = MFMA32(wh, ah[k0i].s, cq[p]);
          cq[p] = MFMA32(wh, al[k0i].s, cq[p]);
          cq[p] = MFMA32(wlo, ah[k0i].s, cq[p]);
        }
        {
          const int fi = 4 + p * 2 + k0i;
          short8 wh = *(const short8*)&wldsHi[e][fi][l * 8];
          short8 wlo = *(const short8*)&wfe[fi * 512 + l * 8];
          ck[p] = MFMA32(wh, ah[k0i].s, ck[p]);
          ck[p] = MFMA32(wh, al[k0i].s, ck[p]);
          ck[p] = MFMA32(wlo, ah[k0i].s, ck[p]);
        }
        {
          const int fi = 8 + p * 2 + k0i;
          short8 wh = *(const short8*)&wldsHi[e][fi][l * 8];
          short8 wlo = *(const short8*)&wfe[fi * 512 + l * 8];
          cv[p] = MFMA32(ah[k0i].s, wh, cv[p]);
          cv[p] = MFMA32(ah[k0i].s, wlo, cv[p]);
          cv[p] = MFMA32(al[k0i].s, wh, cv[p]);
        }
      }
    __builtin_amdgcn_s_setprio(0);

    S4 cqh[2], cql[2], ckh[2], ckl[2], va[2];
    #pragma unroll
    for (int p = 0; p < 2; ++p) {
      cqh[p].u[0] = pk_hi(cq[p][0], cq[p][1]);
      cqh[p].u[1] = pk_hi(cq[p][2], cq[p][3]);
      cql[p].u[0] = pk_hi(cq[p][0] - btrunc(cq[p][0]), cq[p][1] - btrunc(cq[p][1]));
      cql[p].u[1] = pk_hi(cq[p][2] - btrunc(cq[p][2]), cq[p][3] - btrunc(cq[p][3]));
      ckh[p].u[0] = pk_hi(ck[p][0], ck[p][1]);
      ckh[p].u[1] = pk_hi(ck[p][2], ck[p][3]);
      ckl[p].u[0] = pk_hi(ck[p][0] - btrunc(ck[p][0]), ck[p][1] - btrunc(ck[p][1]));
      ckl[p].u[1] = pk_hi(ck[p][2] - btrunc(ck[p][2]), ck[p][3] - btrunc(ck[p][3]));
      va[p].u[0] = pk_rnd(cv[p][0], cv[p][1]);
      va[p].u[1] = pk_rnd(cv[p][2], cv[p][3]);
    }

    f32x4 eng = fz;
    #pragma unroll
    for (int p = 0; p < 2; ++p) {
      eng = MFMA16(ckh[p].s, cqh[p].s, eng);
      eng = MFMA16(ckh[p].s, cql[p].s, eng);
      eng = MFMA16(ckl[p].s, cqh[p].s, eng);
    }

    float w[4];
    {
      float mloc = -1e30f;
      if (g < 3) {
        mloc = eng[0];
        #pragma unroll
        for (int r = 1; r < 4; ++r) mloc = fmaxf(mloc, eng[r]);
      }
      float mx = mloc;
      mx = fmaxf(mx, __shfl_xor(mx, 16));
      mx = fmaxf(mx, __shfl_xor(mx, 32));
      float sloc = 0.f;
      #pragma unroll
      for (int r = 0; r < 4; ++r) {
        w[r] = (g < 3) ? __expf(eng[r] - mx) : 0.f;
        sloc += w[r];
      }
      float sm = sloc;
      sm += __shfl_xor(sm, 16);
      sm += __shfl_xor(sm, 32);
      float inv = 1.f / sm;
      #pragma unroll
      for (int r = 0; r < 4; ++r) w[r] *= inv;
    }

    S4 wh_, wl_;
    wh_.u[0] = pk_hi(w[0], w[1]);
    wh_.u[1] = pk_hi(w[2], w[3]);
    wl_.u[0] = pk_hi(w[0] - btrunc(w[0]), w[1] - btrunc(w[1]));
    wl_.u[1] = pk_hi(w[2] - btrunc(w[2]), w[3] - btrunc(w[3]));
    f32x4 hat[2];
    #pragma unroll
    for (int p = 0; p < 2; ++p) {
      hat[p] = MFMA16(va[p].s, wh_.s, fz);
      hat[p] = MFMA16(va[p].s, wl_.s, hat[p]);
    }

    float dot = 0.f, na = 0.f, nb = 0.f;
    #pragma unroll
    for (int p = 0; p < 2; ++p)
      #pragma unroll
      for (int r = 0; r < 4; ++r) {
        float a = cmem[p][r], h = hat[p][r];
        dot += a * h; na += a * a; nb += h * h;
      }
    dot += __shfl_xor(dot, 16); dot += __shfl_xor(dot, 32);
    na  += __shfl_xor(na, 16);  na  += __shfl_xor(na, 32);
    nb  += __shfl_xor(nb, 16);  nb  += __shfl_xor(nb, 32);
    if (g == 0 && c < kT) {
      float cvv = dot / fmaxf(sqrtf(na) * sqrtf(nb), 1e-8f);
      out[(size_t)site * (kT * kE) + c * kE + e] = cvv;
    }
  };

  // ---- unroll-2 site sweep; 6 tasks/group, strict hA/hB alternation ----
  float hA[16], hB[16], pA[3], pB[3];
  f32x4 cmem[2];
  int site = b * kWaves + wv;
  load_h(h0, site, hA);
  load_p(site, pA);
  for (int it = 0; it < kIters; it += 2) {
    const int s1 = site, s2 = site + kStride;
    // s1: e0(hA) e1(hB) e2(hA)
    load_h(h1, s1, hB);
    if (s1 < kSites) { memfn(pA, cmem); body(s1, 0, hA, cmem); }
    load_h(h2, s1, hA);
    if (s1 < kSites) body(s1, 1, hB, cmem);
    load_h(h0, s2, hB);
    load_p(s2, pB);
    if (s1 < kSites) body(s1, 2, hA, cmem);
    // s2: e0(hB) e1(hA) e2(hB)
    load_h(h1, s2, hA);
    if (s2 < kSites) { memfn(pB, cmem); body(s2, 0, hB, cmem); }
    load_h(h2, s2, hB);
    if (s2 < kSites) body(s2, 1, hA, cmem);
    load_h(h0, s2 + kStride, hA);
    load_p(s2 + kStride, pA);
    if (s2 < kSites) body(s2, 2, hB, cmem);
    site += 2 * kStride;
  }
}

}  // namespace

extern "C" void kernel_launch(void* const* d_in, const int* in_sizes, int n_in,
                              void* d_out, int out_size, void* d_ws, size_t ws_size,
                              hipStream_t stream) {
  const float* input = (const float*)d_in[0];
  const float* h0    = (const float*)d_in[1];
  const float* h1    = (const float*)d_in[2];
  const float* h2    = (const float*)d_in[3];
  const float* memw  = (const float*)d_in[4];
  const float* iq    = (const float*)d_in[5];
  const float* hq    = (const float*)d_in[6];
  const float* kw    = (const float*)d_in[7];
  const float* vw    = (const float*)d_in[8];
  float* out = (float*)d_out;

  unsigned short* wflo = (unsigned short*)d_ws;   // 36864 B

  testam_prep<<<1, kThreads, 0, stream>>>(hq, kw, vw, wflo);
  testam_mfma<<<kNB, kThreads, 0, stream>>>(input, h0, h1, h2, memw, iq, hq, kw, vw,
                                            wflo, out);
}

// Round 21
// 73.983 us; speedup vs baseline: 4.4123x; 1.6042x over previous
//
#include <hip/hip_runtime.h>
#include <math.h>

typedef __attribute__((ext_vector_type(8))) short short8;
typedef __attribute__((ext_vector_type(4))) short short4v;
typedef __attribute__((ext_vector_type(4))) float f32x4;

namespace {

constexpr int kT = 12, kMS = 20, kE = 3;
constexpr int kSites = 64 * 325;                 // 20800
constexpr int kWaves = 16;                       // 1024-thread blocks (R21)
constexpr int kThreads = kWaves * 64;            // 1024
constexpr int kNB = 512;                         // 2 blocks/CU: LDS 74.2KBx2<=160KB,
                                                 // threads 2048 = CU cap
constexpr int kStride = kNB * kWaves;            // 8192
constexpr int kIters = 4;                        // ceil(20800/8192)=3, padded even;
                                                 // iter 3 fully clamped (cheap)

__device__ __forceinline__ void split1(float x, unsigned& hi, unsigned& lo) {
  unsigned u = __float_as_uint(x);
  hi = u >> 16;
  float r = x - __uint_as_float(u & 0xFFFF0000u);   // exact (Sterbenz)
  lo = __float_as_uint(r) >> 16;
}
__device__ __forceinline__ float btrunc(float x) {
  return __uint_as_float(__float_as_uint(x) & 0xFFFF0000u);
}
__device__ __forceinline__ unsigned pk_hi(float a, float b) {   // {bf(b):bf(a)}, a low
  return __builtin_amdgcn_perm(__float_as_uint(b), __float_as_uint(a), 0x07060302u);
}
__device__ __forceinline__ unsigned pk_rnd(float a, float b) {  // round-half-up bf16 pack
  return __builtin_amdgcn_perm(__float_as_uint(b) + 0x8000u,
                               __float_as_uint(a) + 0x8000u, 0x07060302u);
}

union S8 { short8 s; unsigned u[4]; };
union S4 { short4v s; unsigned u[2]; };

#define MFMA32(a, b, c) __builtin_amdgcn_mfma_f32_16x16x32_bf16((a), (b), (c), 0, 0, 0)
// gfx90a+ name on gfx950. No __has_builtin guard — false in the HIP host pass (R10).
#define MFMA16(a, b, c) __builtin_amdgcn_mfma_f32_16x16x16bf16_1k((a), (b), (c), 0, 0, 0)

// Layouts (m89-verified K=32; classic K=16):
//   K=32 A: lane holds A[row=l&15][k=8g+j]; B: B[k=8g+j][col=l&15]
//   K=16 A: lane holds A[row=l&15][k=4g+j]; B: B[k=4g+j][col=l&15]
//   C/D (both): lane holds D[row=4g+r][col=l&15]
// => C-regs of X == A-frag(K=16) of X^T == B-frag(K=16) of X.  (zero-move chaining)
// R8/R12/R19/R20 lesson (x4): ANY added register pressure or tightened bounds
// => allocator spills to scratch (never uses 65-128 VGPR). Bounds stay at 4,
// body liveness frozen. R13: chain-split neutral. R18: mem path deduped once/site.
// R21: 16-wave blocks -> 2 blocks/CU -> 32 waves/CU (needs VGPR<=64; body is 60).
__global__ __launch_bounds__(kThreads, 4) void testam_mfma(
    const float* __restrict__ input, const float* __restrict__ h0,
    const float* __restrict__ h1, const float* __restrict__ h2,
    const float* __restrict__ memw, const float* __restrict__ iq,
    const float* __restrict__ hq, const float* __restrict__ kwt,
    const float* __restrict__ vw, float* __restrict__ out) {

  __shared__ __align__(16) unsigned short wlds[kE][2][12][512];  // 72KB: all experts
  __shared__ __align__(16) float Glds[32][4];                    // G^T = (iq@memw^T)^T

  const int tid = threadIdx.x;
  const int b = blockIdx.x;
  const int l = tid & 63, wv = tid >> 6;
  const int g = l >> 4, c = l & 15;

  // ---- one-time staging: 3 experts' QKV weight frags (K=32) into LDS ----
  for (int idx = tid; idx < kE * 768; idx += kThreads) {
    int e2 = idx / 768, rem = idx - e2 * 768;
    int ll = rem & 63, fi = rem >> 6;
    int mat = fi >> 2, x = (fi >> 1) & 1, y = fi & 1;
    int gg = ll >> 4, cc = ll & 15;
    const float* wp = ((mat == 0) ? hq : (mat == 1) ? kwt : vw) + e2 * 2048
                      + (y * 32 + gg * 8) * 32 + x * 16 + cc;
    short8 sh, sl;
    #pragma unroll
    for (int j = 0; j < 8; ++j) {
      unsigned h, lo; split1(wp[j * 32], h, lo);
      sh[j] = (short)h; sl[j] = (short)lo;
    }
    *(short8*)&wlds[e2][0][fi][ll * 8] = sh;
    *(short8*)&wlds[e2][1][fi][ll * 8] = sl;
  }
  for (int idx = tid; idx < 128; idx += kThreads) {
    int s = idx >> 2, d = idx & 3;
    float acc = 0.f;
    if (d < 3 && s < kMS) {
      for (int m = 0; m < 32; ++m) acc += iq[d * 32 + m] * memw[s * 32 + m];
    }
    Glds[s][d] = acc;
  }

  // ---- memw^T A-frags (K=16) straight into registers (once) ----
  S4 mwh[2][2], mwl[2][2];
  #pragma unroll
  for (int p = 0; p < 2; ++p)
    #pragma unroll
    for (int sch = 0; sch < 2; ++sch) {
      float v[4];
      #pragma unroll
      for (int j = 0; j < 4; ++j) {
        int s = 16 * sch + 4 * g + j;
        v[j] = (s < kMS) ? memw[s * 32 + 16 * p + c] : 0.f;
      }
      mwh[p][sch].u[0] = pk_hi(v[0], v[1]);
      mwh[p][sch].u[1] = pk_hi(v[2], v[3]);
      mwl[p][sch].u[0] = pk_hi(v[0] - btrunc(v[0]), v[1] - btrunc(v[1]));
      mwl[p][sch].u[1] = pk_hi(v[2] - btrunc(v[2]), v[3] - btrunc(v[3]));
    }
  __syncthreads();

  const f32x4 fz = {0.f, 0.f, 0.f, 0.f};

  // lanes c>=12 read row 0 (finite); s>=12 slots meet exact-zero weights.
  const int crow = (c < kT) ? c : 0;

  auto load_h = [&](const float* hb, int s, float* hr) {
    const int sc_ = (s < kSites) ? s : (kSites - 1);
    const float* p = hb + (size_t)sc_ * 768 + crow * 64 + g * 8;
    *(f32x4*)&hr[0]  = *(const f32x4*)&p[0];
    *(f32x4*)&hr[4]  = *(const f32x4*)&p[4];
    *(f32x4*)&hr[8]  = *(const f32x4*)&p[32];
    *(f32x4*)&hr[12] = *(const f32x4*)&p[36];
  };
  auto load_p = [&](int s, float* pr) {
    const int sc_ = (s < kSites) ? s : (kSites - 1);
    const float* ip = input + (size_t)sc_ * 36 + crow * 3;
    pr[0] = ip[0]; pr[1] = ip[1]; pr[2] = ip[2];
  };

  // ---- expert-invariant memory path: pv -> cmem[2] (once per site) ----
  auto memfn = [&](const float* pv, f32x4* cmem) {
    float sc0[4], sc1[4];
    #pragma unroll
    for (int r = 0; r < 4; ++r) {
      const f32x4 Gv0 = *(const f32x4*)&Glds[4 * g + r][0];
      sc0[r] = pv[0] * Gv0[0] + pv[1] * Gv0[1] + pv[2] * Gv0[2];
      const f32x4 Gv1 = *(const f32x4*)&Glds[16 + 4 * g + r][0];
      sc1[r] = pv[0] * Gv1[0] + pv[1] * Gv1[1] + pv[2] * Gv1[2];
    }
    float w0[4], w1[4];
    {
      float mloc = sc0[0];
      #pragma unroll
      for (int r = 1; r < 4; ++r) mloc = fmaxf(mloc, sc0[r]);
      if (g == 0) {
        #pragma unroll
        for (int r = 0; r < 4; ++r) mloc = fmaxf(mloc, sc1[r]);
      }
      float mx = mloc;
      mx = fmaxf(mx, __shfl_xor(mx, 16));
      mx = fmaxf(mx, __shfl_xor(mx, 32));
      float sloc = 0.f;
      #pragma unroll
      for (int r = 0; r < 4; ++r) {
        w0[r] = __expf(sc0[r] - mx); sloc += w0[r];
        w1[r] = (g == 0) ? __expf(sc1[r] - mx) : 0.f; sloc += w1[r];
      }
      float sm = sloc;
      sm += __shfl_xor(sm, 16);
      sm += __shfl_xor(sm, 32);
      float inv = 1.f / sm;
      #pragma unroll
      for (int r = 0; r < 4; ++r) { w0[r] *= inv; w1[r] *= inv; }
    }
    S4 w0h, w0l, w1h, w1l;
    w0h.u[0] = pk_hi(w0[0], w0[1]);  w0h.u[1] = pk_hi(w0[2], w0[3]);
    w0l.u[0] = pk_hi(w0[0] - btrunc(w0[0]), w0[1] - btrunc(w0[1]));
    w0l.u[1] = pk_hi(w0[2] - btrunc(w0[2]), w0[3] - btrunc(w0[3]));
    w1h.u[0] = pk_hi(w1[0], w1[1]);  w1h.u[1] = pk_hi(w1[2], w1[3]);
    w1l.u[0] = pk_hi(w1[0] - btrunc(w1[0]), w1[1] - btrunc(w1[1]));
    w1l.u[1] = pk_hi(w1[2] - btrunc(w1[2]), w1[3] - btrunc(w1[3]));
    #pragma unroll
    for (int p = 0; p < 2; ++p) {
      cmem[p] = MFMA16(mwh[p][0].s, w0h.s, fz);
      cmem[p] = MFMA16(mwh[p][0].s, w0l.s, cmem[p]);
      cmem[p] = MFMA16(mwl[p][0].s, w0h.s, cmem[p]);
      cmem[p] = MFMA16(mwh[p][1].s, w1h.s, cmem[p]);
      cmem[p] = MFMA16(mwh[p][1].s, w1l.s, cmem[p]);
      cmem[p] = MFMA16(mwl[p][1].s, w1h.s, cmem[p]);
    }
  };

  // ---- per-(site, expert) attention path + cosine + store ----
  auto body = [&](int site, int e, const float* hv, const f32x4* cmem) {
    S8 ah[2], al[2];
    #pragma unroll
    for (int k0i = 0; k0i < 2; ++k0i)
      #pragma unroll
      for (int jj = 0; jj < 4; ++jj) {
        float a = hv[k0i * 8 + 2 * jj], bb = hv[k0i * 8 + 2 * jj + 1];
        ah[k0i].u[jj] = pk_hi(a, bb);
        al[k0i].u[jj] = pk_hi(a - btrunc(a), bb - btrunc(bb));
      }

    f32x4 cq[2] = {fz, fz}, ck[2] = {fz, fz}, cv[2] = {fz, fz};
    __builtin_amdgcn_s_setprio(1);
    #pragma unroll
    for (int p = 0; p < 2; ++p)
      #pragma unroll
      for (int k0i = 0; k0i < 2; ++k0i) {
        {
          const int fi = 0 + p * 2 + k0i;
          short8 wh = *(const short8*)&wlds[e][0][fi][l * 8];
          short8 wlo = *(const short8*)&wlds[e][1][fi][l * 8];
          cq[p] = MFMA32(wh, ah[k0i].s, cq[p]);
          cq[p] = MFMA32(wh, al[k0i].s, cq[p]);
          cq[p] = MFMA32(wlo, ah[k0i].s, cq[p]);
        }
        {
          const int fi = 4 + p * 2 + k0i;
          short8 wh = *(const short8*)&wlds[e][0][fi][l * 8];
          short8 wlo = *(const short8*)&wlds[e][1][fi][l * 8];
          ck[p] = MFMA32(wh, ah[k0i].s, ck[p]);
          ck[p] = MFMA32(wh, al[k0i].s, ck[p]);
          ck[p] = MFMA32(wlo, ah[k0i].s, ck[p]);
        }
        {
          const int fi = 8 + p * 2 + k0i;
          short8 wh = *(const short8*)&wlds[e][0][fi][l * 8];
          short8 wlo = *(const short8*)&wlds[e][1][fi][l * 8];
          cv[p] = MFMA32(ah[k0i].s, wh, cv[p]);
          cv[p] = MFMA32(ah[k0i].s, wlo, cv[p]);
          cv[p] = MFMA32(al[k0i].s, wh, cv[p]);
        }
      }
    __builtin_amdgcn_s_setprio(0);

    S4 cqh[2], cql[2], ckh[2], ckl[2], va[2];
    #pragma unroll
    for (int p = 0; p < 2; ++p) {
      cqh[p].u[0] = pk_hi(cq[p][0], cq[p][1]);
      cqh[p].u[1] = pk_hi(cq[p][2], cq[p][3]);
      cql[p].u[0] = pk_hi(cq[p][0] - btrunc(cq[p][0]), cq[p][1] - btrunc(cq[p][1]));
      cql[p].u[1] = pk_hi(cq[p][2] - btrunc(cq[p][2]), cq[p][3] - btrunc(cq[p][3]));
      ckh[p].u[0] = pk_hi(ck[p][0], ck[p][1]);
      ckh[p].u[1] = pk_hi(ck[p][2], ck[p][3]);
      ckl[p].u[0] = pk_hi(ck[p][0] - btrunc(ck[p][0]), ck[p][1] - btrunc(ck[p][1]));
      ckl[p].u[1] = pk_hi(ck[p][2] - btrunc(ck[p][2]), ck[p][3] - btrunc(ck[p][3]));
      va[p].u[0] = pk_rnd(cv[p][0], cv[p][1]);
      va[p].u[1] = pk_rnd(cv[p][2], cv[p][3]);
    }

    f32x4 eng = fz;
    #pragma unroll
    for (int p = 0; p < 2; ++p) {
      eng = MFMA16(ckh[p].s, cqh[p].s, eng);
      eng = MFMA16(ckh[p].s, cql[p].s, eng);
      eng = MFMA16(ckl[p].s, cqh[p].s, eng);
    }

    float w[4];
    {
      float mloc = -1e30f;
      if (g < 3) {
        mloc = eng[0];
        #pragma unroll
        for (int r = 1; r < 4; ++r) mloc = fmaxf(mloc, eng[r]);
      }
      float mx = mloc;
      mx = fmaxf(mx, __shfl_xor(mx, 16));
      mx = fmaxf(mx, __shfl_xor(mx, 32));
      float sloc = 0.f;
      #pragma unroll
      for (int r = 0; r < 4; ++r) {
        w[r] = (g < 3) ? __expf(eng[r] - mx) : 0.f;
        sloc += w[r];
      }
      float sm = sloc;
      sm += __shfl_xor(sm, 16);
      sm += __shfl_xor(sm, 32);
      float inv = 1.f / sm;
      #pragma unroll
      for (int r = 0; r < 4; ++r) w[r] *= inv;
    }

    S4 wh_, wl_;
    wh_.u[0] = pk_hi(w[0], w[1]);
    wh_.u[1] = pk_hi(w[2], w[3]);
    wl_.u[0] = pk_hi(w[0] - btrunc(w[0]), w[1] - btrunc(w[1]));
    wl_.u[1] = pk_hi(w[2] - btrunc(w[2]), w[3] - btrunc(w[3]));
    f32x4 hat[2];
    #pragma unroll
    for (int p = 0; p < 2; ++p) {
      hat[p] = MFMA16(va[p].s, wh_.s, fz);
      hat[p] = MFMA16(va[p].s, wl_.s, hat[p]);
    }

    float dot = 0.f, na = 0.f, nb = 0.f;
    #pragma unroll
    for (int p = 0; p < 2; ++p)
      #pragma unroll
      for (int r = 0; r < 4; ++r) {
        float a = cmem[p][r], h = hat[p][r];
        dot += a * h; na += a * a; nb += h * h;
      }
    dot += __shfl_xor(dot, 16); dot += __shfl_xor(dot, 32);
    na  += __shfl_xor(na, 16);  na  += __shfl_xor(na, 32);
    nb  += __shfl_xor(nb, 16);  nb  += __shfl_xor(nb, 32);
    if (g == 0 && c < kT) {
      float cvv = dot / fmaxf(sqrtf(na) * sqrtf(nb), 1e-8f);
      out[(size_t)site * (kT * kE) + c * kE + e] = cvv;
    }
  };

  // ---- unroll-2 site sweep; 6 tasks/group, strict hA/hB alternation ----
  float hA[16], hB[16], pA[3], pB[3];
  f32x4 cmem[2];
  int site = b * kWaves + wv;
  load_h(h0, site, hA);
  load_p(site, pA);
  for (int it = 0; it < kIters; it += 2) {
    const int s1 = site, s2 = site + kStride;
    // s1: e0(hA) e1(hB) e2(hA)
    load_h(h1, s1, hB);
    if (s1 < kSites) { memfn(pA, cmem); body(s1, 0, hA, cmem); }
    load_h(h2, s1, hA);
    if (s1 < kSites) body(s1, 1, hB, cmem);
    load_h(h0, s2, hB);
    load_p(s2, pB);
    if (s1 < kSites) body(s1, 2, hA, cmem);
    // s2: e0(hB) e1(hA) e2(hB)
    load_h(h1, s2, hA);
    if (s2 < kSites) { memfn(pB, cmem); body(s2, 0, hB, cmem); }
    load_h(h2, s2, hB);
    if (s2 < kSites) body(s2, 1, hA, cmem);
    load_h(h0, s2 + kStride, hA);
    load_p(s2 + kStride, pA);
    if (s2 < kSites) body(s2, 2, hB, cmem);
    site += 2 * kStride;
  }
}

}  // namespace

extern "C" void kernel_launch(void* const* d_in, const int* in_sizes, int n_in,
                              void* d_out, int out_size, void* d_ws, size_t ws_size,
                              hipStream_t stream) {
  const float* input = (const float*)d_in[0];
  const float* h0    = (const float*)d_in[1];
  const float* h1    = (const float*)d_in[2];
  const float* h2    = (const float*)d_in[3];
  const float* memw  = (const float*)d_in[4];
  const float* iq    = (const float*)d_in[5];
  const float* hq    = (const float*)d_in[6];
  const float* kw    = (const float*)d_in[7];
  const float* vw    = (const float*)d_in[8];
  float* out = (float*)d_out;

  testam_mfma<<<kNB, kThreads, 0, stream>>>(
      input, h0, h1, h2, memw, iq, hq, kw, vw, out);
}

// Round 22
// 64.093 us; speedup vs baseline: 5.0931x; 1.1543x over previous
//
#include <hip/hip_runtime.h>
#include <math.h>

typedef __attribute__((ext_vector_type(8))) short short8;
typedef __attribute__((ext_vector_type(4))) short short4v;
typedef __attribute__((ext_vector_type(4))) float f32x4;

namespace {

constexpr int kT = 12, kMS = 20, kE = 3;
constexpr int kSites = 64 * 325;                 // 20800
constexpr int kWaves = 8;
constexpr int kThreads = kWaves * 64;            // 512
constexpr int kNB = 512;                         // blocks total (2/CU exactly at 72.5KB LDS)
constexpr int kStride = kNB * kWaves;            // 4096
constexpr int kIters = (kSites + kStride - 1) / kStride;  // 6 (even -> unroll-2 clean)

__device__ __forceinline__ void split1(float x, unsigned& hi, unsigned& lo) {
  unsigned u = __float_as_uint(x);
  hi = u >> 16;
  float r = x - __uint_as_float(u & 0xFFFF0000u);   // exact (Sterbenz)
  lo = __float_as_uint(r) >> 16;
}
__device__ __forceinline__ float btrunc(float x) {
  return __uint_as_float(__float_as_uint(x) & 0xFFFF0000u);
}
__device__ __forceinline__ unsigned pk_hi(float a, float b) {   // {bf(b):bf(a)}, a low
  return __builtin_amdgcn_perm(__float_as_uint(b), __float_as_uint(a), 0x07060302u);
}
__device__ __forceinline__ unsigned pk_rnd(float a, float b) {  // round-half-up bf16 pack
  return __builtin_amdgcn_perm(__float_as_uint(b) + 0x8000u,
                               __float_as_uint(a) + 0x8000u, 0x07060302u);
}

union S8 { short8 s; unsigned u[4]; };
union S4 { short4v s; unsigned u[2]; };

#define MFMA32(a, b, c) __builtin_amdgcn_mfma_f32_16x16x32_bf16((a), (b), (c), 0, 0, 0)
// gfx90a+ name on gfx950. No __has_builtin guard — false in the HIP host pass (R10).
#define MFMA16(a, b, c) __builtin_amdgcn_mfma_f32_16x16x16bf16_1k((a), (b), (c), 0, 0, 0)

// Layouts (m89-verified K=32; classic K=16):
//   K=32 A: lane holds A[row=l&15][k=8g+j]; B: B[k=8g+j][col=l&15]
//   K=16 A: lane holds A[row=l&15][k=4g+j]; B: B[k=4g+j][col=l&15]
//   C/D (both): lane holds D[row=4g+r][col=l&15]
// => C-regs of X == A-frag(K=16) of X^T == B-frag(K=16) of X.  (zero-move chaining)
// R8/R12/R19/R20 (x4): any added liveness or tightened bounds => scratch spill.
// R13: chain-split neutral. R21: 16-wave blocks don't raise occupancy.
// R18 (this kernel): all 3 experts per block; memory path computed ONCE per site.
__global__ __launch_bounds__(kThreads, 4) void testam_mfma(
    const float* __restrict__ input, const float* __restrict__ h0,
    const float* __restrict__ h1, const float* __restrict__ h2,
    const float* __restrict__ memw, const float* __restrict__ iq,
    const float* __restrict__ hq, const float* __restrict__ kwt,
    const float* __restrict__ vw, float* __restrict__ out) {

  __shared__ __align__(16) unsigned short wlds[kE][2][12][512];  // 72KB: all experts
  __shared__ __align__(16) float Glds[32][4];                    // G^T = (iq@memw^T)^T

  const int tid = threadIdx.x;
  const int b = blockIdx.x;
  const int l = tid & 63, wv = tid >> 6;
  const int g = l >> 4, c = l & 15;

  // ---- one-time staging: 3 experts' QKV weight frags (K=32) into LDS ----
  for (int idx = tid; idx < kE * 768; idx += kThreads) {
    int e2 = idx / 768, rem = idx - e2 * 768;
    int ll = rem & 63, fi = rem >> 6;
    int mat = fi >> 2, x = (fi >> 1) & 1, y = fi & 1;
    int gg = ll >> 4, cc = ll & 15;
    const float* wp = ((mat == 0) ? hq : (mat == 1) ? kwt : vw) + e2 * 2048
                      + (y * 32 + gg * 8) * 32 + x * 16 + cc;
    short8 sh, sl;
    #pragma unroll
    for (int j = 0; j < 8; ++j) {
      unsigned h, lo; split1(wp[j * 32], h, lo);
      sh[j] = (short)h; sl[j] = (short)lo;
    }
    *(short8*)&wlds[e2][0][fi][ll * 8] = sh;
    *(short8*)&wlds[e2][1][fi][ll * 8] = sl;
  }
  for (int idx = tid; idx < 128; idx += kThreads) {
    int s = idx >> 2, d = idx & 3;
    float acc = 0.f;
    if (d < 3 && s < kMS) {
      for (int m = 0; m < 32; ++m) acc += iq[d * 32 + m] * memw[s * 32 + m];
    }
    Glds[s][d] = acc;
  }

  // ---- memw^T A-frags (K=16) straight into registers (once) ----
  S4 mwh[2][2], mwl[2][2];
  #pragma unroll
  for (int p = 0; p < 2; ++p)
    #pragma unroll
    for (int sch = 0; sch < 2; ++sch) {
      float v[4];
      #pragma unroll
      for (int j = 0; j < 4; ++j) {
        int s = 16 * sch + 4 * g + j;
        v[j] = (s < kMS) ? memw[s * 32 + 16 * p + c] : 0.f;
      }
      mwh[p][sch].u[0] = pk_hi(v[0], v[1]);
      mwh[p][sch].u[1] = pk_hi(v[2], v[3]);
      mwl[p][sch].u[0] = pk_hi(v[0] - btrunc(v[0]), v[1] - btrunc(v[1]));
      mwl[p][sch].u[1] = pk_hi(v[2] - btrunc(v[2]), v[3] - btrunc(v[3]));
    }
  __syncthreads();

  const f32x4 fz = {0.f, 0.f, 0.f, 0.f};

  // lanes c>=12 read row 0 (finite); s>=12 slots meet exact-zero weights.
  const int crow = (c < kT) ? c : 0;

  auto load_h = [&](const float* hb, int s, float* hr) {
    const int sc_ = (s < kSites) ? s : (kSites - 1);
    const float* p = hb + (size_t)sc_ * 768 + crow * 64 + g * 8;
    *(f32x4*)&hr[0]  = *(const f32x4*)&p[0];
    *(f32x4*)&hr[4]  = *(const f32x4*)&p[4];
    *(f32x4*)&hr[8]  = *(const f32x4*)&p[32];
    *(f32x4*)&hr[12] = *(const f32x4*)&p[36];
  };
  auto load_p = [&](int s, float* pr) {
    const int sc_ = (s < kSites) ? s : (kSites - 1);
    const float* ip = input + (size_t)sc_ * 36 + crow * 3;
    pr[0] = ip[0]; pr[1] = ip[1]; pr[2] = ip[2];
  };

  // ---- expert-invariant memory path: pv -> cmem[2] (once per site) ----
  auto memfn = [&](const float* pv, f32x4* cmem) {
    float sc0[4], sc1[4];
    #pragma unroll
    for (int r = 0; r < 4; ++r) {
      const f32x4 Gv0 = *(const f32x4*)&Glds[4 * g + r][0];
      sc0[r] = pv[0] * Gv0[0] + pv[1] * Gv0[1] + pv[2] * Gv0[2];
      const f32x4 Gv1 = *(const f32x4*)&Glds[16 + 4 * g + r][0];
      sc1[r] = pv[0] * Gv1[0] + pv[1] * Gv1[1] + pv[2] * Gv1[2];
    }
    float w0[4], w1[4];
    {
      float mloc = sc0[0];
      #pragma unroll
      for (int r = 1; r < 4; ++r) mloc = fmaxf(mloc, sc0[r]);
      if (g == 0) {
        #pragma unroll
        for (int r = 0; r < 4; ++r) mloc = fmaxf(mloc, sc1[r]);
      }
      float mx = mloc;
      mx = fmaxf(mx, __shfl_xor(mx, 16));
      mx = fmaxf(mx, __shfl_xor(mx, 32));
      float sloc = 0.f;
      #pragma unroll
      for (int r = 0; r < 4; ++r) {
        w0[r] = __expf(sc0[r] - mx); sloc += w0[r];
        w1[r] = (g == 0) ? __expf(sc1[r] - mx) : 0.f; sloc += w1[r];
      }
      float sm = sloc;
      sm += __shfl_xor(sm, 16);
      sm += __shfl_xor(sm, 32);
      float inv = 1.f / sm;
      #pragma unroll
      for (int r = 0; r < 4; ++r) { w0[r] *= inv; w1[r] *= inv; }
    }
    S4 w0h, w0l, w1h, w1l;
    w0h.u[0] = pk_hi(w0[0], w0[1]);  w0h.u[1] = pk_hi(w0[2], w0[3]);
    w0l.u[0] = pk_hi(w0[0] - btrunc(w0[0]), w0[1] - btrunc(w0[1]));
    w0l.u[1] = pk_hi(w0[2] - btrunc(w0[2]), w0[3] - btrunc(w0[3]));
    w1h.u[0] = pk_hi(w1[0], w1[1]);  w1h.u[1] = pk_hi(w1[2], w1[3]);
    w1l.u[0] = pk_hi(w1[0] - btrunc(w1[0]), w1[1] - btrunc(w1[1]));
    w1l.u[1] = pk_hi(w1[2] - btrunc(w1[2]), w1[3] - btrunc(w1[3]));
    #pragma unroll
    for (int p = 0; p < 2; ++p) {
      cmem[p] = MFMA16(mwh[p][0].s, w0h.s, fz);
      cmem[p] = MFMA16(mwh[p][0].s, w0l.s, cmem[p]);
      cmem[p] = MFMA16(mwl[p][0].s, w0h.s, cmem[p]);
      cmem[p] = MFMA16(mwh[p][1].s, w1h.s, cmem[p]);
      cmem[p] = MFMA16(mwh[p][1].s, w1l.s, cmem[p]);
      cmem[p] = MFMA16(mwl[p][1].s, w1h.s, cmem[p]);
    }
  };

  // ---- per-(site, expert) attention path + cosine + store ----
  auto body = [&](int site, int e, const float* hv, const f32x4* cmem) {
    S8 ah[2], al[2];
    #pragma unroll
    for (int k0i = 0; k0i < 2; ++k0i)
      #pragma unroll
      for (int jj = 0; jj < 4; ++jj) {
        float a = hv[k0i * 8 + 2 * jj], bb = hv[k0i * 8 + 2 * jj + 1];
        ah[k0i].u[jj] = pk_hi(a, bb);
        al[k0i].u[jj] = pk_hi(a - btrunc(a), bb - btrunc(bb));
      }

    f32x4 cq[2] = {fz, fz}, ck[2] = {fz, fz}, cv[2] = {fz, fz};
    __builtin_amdgcn_s_setprio(1);
    #pragma unroll
    for (int p = 0; p < 2; ++p)
      #pragma unroll
      for (int k0i = 0; k0i < 2; ++k0i) {
        {
          const int fi = 0 + p * 2 + k0i;
          short8 wh = *(const short8*)&wlds[e][0][fi][l * 8];
          short8 wlo = *(const short8*)&wlds[e][1][fi][l * 8];
          cq[p] = MFMA32(wh, ah[k0i].s, cq[p]);
          cq[p] = MFMA32(wh, al[k0i].s, cq[p]);
          cq[p] = MFMA32(wlo, ah[k0i].s, cq[p]);
        }
        {
          const int fi = 4 + p * 2 + k0i;
          short8 wh = *(const short8*)&wlds[e][0][fi][l * 8];
          short8 wlo = *(const short8*)&wlds[e][1][fi][l * 8];
          ck[p] = MFMA32(wh, ah[k0i].s, ck[p]);
          ck[p] = MFMA32(wh, al[k0i].s, ck[p]);
          ck[p] = MFMA32(wlo, ah[k0i].s, ck[p]);
        }
        {
          const int fi = 8 + p * 2 + k0i;
          short8 wh = *(const short8*)&wlds[e][0][fi][l * 8];
          short8 wlo = *(const short8*)&wlds[e][1][fi][l * 8];
          cv[p] = MFMA32(ah[k0i].s, wh, cv[p]);
          cv[p] = MFMA32(ah[k0i].s, wlo, cv[p]);
          cv[p] = MFMA32(al[k0i].s, wh, cv[p]);
        }
      }
    __builtin_amdgcn_s_setprio(0);

    S4 cqh[2], cql[2], ckh[2], ckl[2], va[2];
    #pragma unroll
    for (int p = 0; p < 2; ++p) {
      cqh[p].u[0] = pk_hi(cq[p][0], cq[p][1]);
      cqh[p].u[1] = pk_hi(cq[p][2], cq[p][3]);
      cql[p].u[0] = pk_hi(cq[p][0] - btrunc(cq[p][0]), cq[p][1] - btrunc(cq[p][1]));
      cql[p].u[1] = pk_hi(cq[p][2] - btrunc(cq[p][2]), cq[p][3] - btrunc(cq[p][3]));
      ckh[p].u[0] = pk_hi(ck[p][0], ck[p][1]);
      ckh[p].u[1] = pk_hi(ck[p][2], ck[p][3]);
      ckl[p].u[0] = pk_hi(ck[p][0] - btrunc(ck[p][0]), ck[p][1] - btrunc(ck[p][1]));
      ckl[p].u[1] = pk_hi(ck[p][2] - btrunc(ck[p][2]), ck[p][3] - btrunc(ck[p][3]));
      va[p].u[0] = pk_rnd(cv[p][0], cv[p][1]);
      va[p].u[1] = pk_rnd(cv[p][2], cv[p][3]);
    }

    f32x4 eng = fz;
    #pragma unroll
    for (int p = 0; p < 2; ++p) {
      eng = MFMA16(ckh[p].s, cqh[p].s, eng);
      eng = MFMA16(ckh[p].s, cql[p].s, eng);
      eng = MFMA16(ckl[p].s, cqh[p].s, eng);
    }

    float w[4];
    {
      float mloc = -1e30f;
      if (g < 3) {
        mloc = eng[0];
        #pragma unroll
        for (int r = 1; r < 4; ++r) mloc = fmaxf(mloc, eng[r]);
      }
      float mx = mloc;
      mx = fmaxf(mx, __shfl_xor(mx, 16));
      mx = fmaxf(mx, __shfl_xor(mx, 32));
      float sloc = 0.f;
      #pragma unroll
      for (int r = 0; r < 4; ++r) {
        w[r] = (g < 3) ? __expf(eng[r] - mx) : 0.f;
        sloc += w[r];
      }
      float sm = sloc;
      sm += __shfl_xor(sm, 16);
      sm += __shfl_xor(sm, 32);
      float inv = 1.f / sm;
      #pragma unroll
      for (int r = 0; r < 4; ++r) w[r] *= inv;
    }

    S4 wh_, wl_;
    wh_.u[0] = pk_hi(w[0], w[1]);
    wh_.u[1] = pk_hi(w[2], w[3]);
    wl_.u[0] = pk_hi(w[0] - btrunc(w[0]), w[1] - btrunc(w[1]));
    wl_.u[1] = pk_hi(w[2] - btrunc(w[2]), w[3] - btrunc(w[3]));
    f32x4 hat[2];
    #pragma unroll
    for (int p = 0; p < 2; ++p) {
      hat[p] = MFMA16(va[p].s, wh_.s, fz);
      hat[p] = MFMA16(va[p].s, wl_.s, hat[p]);
    }

    float dot = 0.f, na = 0.f, nb = 0.f;
    #pragma unroll
    for (int p = 0; p < 2; ++p)
      #pragma unroll
      for (int r = 0; r < 4; ++r) {
        float a = cmem[p][r], h = hat[p][r];
        dot += a * h; na += a * a; nb += h * h;
      }
    dot += __shfl_xor(dot, 16); dot += __shfl_xor(dot, 32);
    na  += __shfl_xor(na, 16);  na  += __shfl_xor(na, 32);
    nb  += __shfl_xor(nb, 16);  nb  += __shfl_xor(nb, 32);
    if (g == 0 && c < kT) {
      float cvv = dot / fmaxf(sqrtf(na) * sqrtf(nb), 1e-8f);
      out[(size_t)site * (kT * kE) + c * kE + e] = cvv;
    }
  };

  // ---- unroll-2 site sweep; 6 tasks/group, strict hA/hB alternation ----
  float hA[16], hB[16], pA[3], pB[3];
  f32x4 cmem[2];
  int site = b * kWaves + wv;
  load_h(h0, site, hA);
  load_p(site, pA);
  for (int it = 0; it < kIters; it += 2) {
    const int s1 = site, s2 = site + kStride;
    // s1: e0(hA) e1(hB) e2(hA)
    load_h(h1, s1, hB);
    if (s1 < kSites) { memfn(pA, cmem); body(s1, 0, hA, cmem); }
    load_h(h2, s1, hA);
    if (s1 < kSites) body(s1, 1, hB, cmem);
    load_h(h0, s2, hB);
    load_p(s2, pB);
    if (s1 < kSites) body(s1, 2, hA, cmem);
    // s2: e0(hB) e1(hA) e2(hB)
    load_h(h1, s2, hA);
    if (s2 < kSites) { memfn(pB, cmem); body(s2, 0, hB, cmem); }
    load_h(h2, s2, hB);
    if (s2 < kSites) body(s2, 1, hA, cmem);
    load_h(h0, s2 + kStride, hA);
    load_p(s2 + kStride, pA);
    if (s2 < kSites) body(s2, 2, hB, cmem);
    site += 2 * kStride;
  }
}

}  // namespace

extern "C" void kernel_launch(void* const* d_in, const int* in_sizes, int n_in,
                              void* d_out, int out_size, void* d_ws, size_t ws_size,
                              hipStream_t stream) {
  const float* input = (const float*)d_in[0];
  const float* h0    = (const float*)d_in[1];
  const float* h1    = (const float*)d_in[2];
  const float* h2    = (const float*)d_in[3];
  const float* memw  = (const float*)d_in[4];
  const float* iq    = (const float*)d_in[5];
  const float* hq    = (const float*)d_in[6];
  const float* kw    = (const float*)d_in[7];
  const float* vw    = (const float*)d_in[8];
  float* out = (float*)d_out;

  testam_mfma<<<kNB, kThreads, 0, stream>>>(
      input, h0, h1, h2, memw, iq, hq, kw, vw, out);
}